// Round 1
// baseline (132.146 us; speedup 1.0000x reference)
//
#include <hip/hip_runtime.h>
#include <math.h>

#define GSZ 512
#define NSZ 256
#define NBATCH 8
#define MPTS 131072
#define PI_F 3.14159265358979f
#define BETA_F 13.8551004f
#define BETA2_F (BETA_F * BETA_F)
#define RSQ2 0.70710678f
// LDS pad: +1 float2 every 8 → strided radix-8 access conflict-reduced
#define PADIDX(i) ((i) + ((i) >> 3))

// ---------------------------------------------------------------- helpers

__device__ __forceinline__ float apod(int i) {
    float x = (float)(i - 128);
    float arg = PI_F * 6.0f * x * (1.0f / 512.0f);
    float t = BETA2_F - arg * arg;
    float st = sqrtf(t);
    return st / sinhf(st);
}

// Branchless Kaiser-Bessel weight, large-x asymptotic i0 (3 transcendentals).
__device__ __forceinline__ float kbw(float u) {
    float t = 1.0f - u * u * (1.0f / 9.0f);
    float x = BETA_F * sqrtf(fmaxf(t, 0.0f));
    float xc = fmaxf(x, 0.35f);
    float R = __builtin_amdgcn_rsqf(xc);
    float R2 = R * R;
    float q = R * (0.39894228f + R2 * (0.04986779f + R2 * 0.02804702f));
    float w = __expf(xc) * q;
    return (t > 0.0f) ? w : 0.0f;
}

// DPP quad_perm cross-lane (no DS pipe)
template<int CTRL>
__device__ __forceinline__ float qdpp(float v) {
    int r = __builtin_amdgcn_mov_dpp(__float_as_int(v), CTRL, 0xF, 0xF, true);
    return __int_as_float(r);
}

__device__ __forceinline__ float2 cadd(float2 a, float2 b){ return make_float2(a.x+b.x, a.y+b.y); }
__device__ __forceinline__ float2 csub(float2 a, float2 b){ return make_float2(a.x-b.x, a.y-b.y); }
__device__ __forceinline__ float2 cmul(float2 a, float2 b){ return make_float2(a.x*b.x-a.y*b.y, a.x*b.y+a.y*b.x); }
__device__ __forceinline__ float2 mul_negi(float2 a){ return make_float2(a.y, -a.x); }
__device__ __forceinline__ float2 mul_posi(float2 a){ return make_float2(-a.y, a.x); }
__device__ __forceinline__ float2 mul_w81(float2 a){ return make_float2(RSQ2*(a.x+a.y), RSQ2*(a.y-a.x)); }
__device__ __forceinline__ float2 mul_w83(float2 a){ return make_float2(RSQ2*(a.y-a.x), -RSQ2*(a.x+a.y)); }

__device__ __forceinline__ void dft8_combine(float2 E0, float2 E1, float2 E2, float2 E3,
                                             float2 O0, float2 O1, float2 O2, float2 O3,
                                             float2* y) {
    float2 c1 = mul_w81(O1), c2 = mul_negi(O2), c3 = mul_w83(O3);
    y[0] = cadd(E0, O0); y[4] = csub(E0, O0);
    y[1] = cadd(E1, c1); y[5] = csub(E1, c1);
    y[2] = cadd(E2, c2); y[6] = csub(E2, c2);
    y[3] = cadd(E3, c3); y[7] = csub(E3, c3);
}

__device__ __forceinline__ void dft8(const float2* x, float2* y) {
    float2 a0=x[0], a1=x[2], a2=x[4], a3=x[6];
    float2 b0=x[1], b1=x[3], b2=x[5], b3=x[7];
    float2 ta0=cadd(a0,a2), ta1=csub(a0,a2), ta2=cadd(a1,a3), ta3=csub(a1,a3);
    float2 E0=cadd(ta0,ta2), E2=csub(ta0,ta2);
    float2 E1=cadd(ta1, mul_negi(ta3)), E3=cadd(ta1, mul_posi(ta3));
    float2 tb0=cadd(b0,b2), tb1=csub(b0,b2), tb2=cadd(b1,b3), tb3=csub(b1,b3);
    float2 O0=cadd(tb0,tb2), O2=csub(tb0,tb2);
    float2 O1=cadd(tb1, mul_negi(tb3)), O3=cadd(tb1, mul_posi(tb3));
    dft8_combine(E0,E1,E2,E3,O0,O1,O2,O3,y);
}

__device__ __forceinline__ void dft8_pruned(float2 x0, float2 x1, float2 x6, float2 x7, float2* y) {
    float2 E0 = cadd(x0, x6), E2 = csub(x0, x6);
    float2 E1 = cadd(x0, mul_posi(x6)), E3 = cadd(x0, mul_negi(x6));
    float2 O0 = cadd(x1, x7), O2 = csub(x1, x7);
    float2 O1 = cadd(x1, mul_posi(x7)), O3 = cadd(x1, mul_negi(x7));
    dft8_combine(E0,E1,E2,E3,O0,O1,O2,O3,y);
}

template<int S>
__device__ __forceinline__ void twiddle8(int t, float2* y) {
    if (S < 2) {
        int j = (S == 0) ? t : (t >> 3);
        const float scale = (S == 0) ? (-2.0f*PI_F/512.0f) : (-2.0f*PI_F/64.0f);
        float theta = scale * (float)j;
        float sn, cs;
        __sincosf(theta, &sn, &cs);              // sin FIRST, cos second
        float2 w = make_float2(cs, sn), wq = w;
        y[1] = cmul(y[1], wq);
        #pragma unroll
        for (int q = 2; q < 8; ++q) { wq = cmul(wq, w); y[q] = cmul(y[q], wq); }
    }
}

// ---------------------------------------------------------------- pass 1
// Batch-pair packed row FFT (r9): z = img_{2p} + i*img_{2p+1}. 2 rows/block.
__global__ __launch_bounds__(128) void pass1_rowfft(const float* __restrict__ image,
                                                    float2* __restrict__ T) {
    __shared__ float2 sm[2][2][578];
    int tid = threadIdx.x;
    int r = tid >> 6, t = tid & 63;                 // r in {0,1}
    int blk = blockIdx.x;
    int p = blk & 3;                                // batch pair 0..3
    int g = blk >> 2;                               // 0..127
    int rp = (g << 1) + r;                          // compact row 0..255
    int y = (rp < 128) ? rp : (rp + 256);
    int iy = (y < 128) ? (y + 128) : (y - 384);
    float ay = apod(iy);
    const float* irow0 = image + ((size_t)((2 * p)     * NSZ + iy)) * NSZ;
    const float* irow1 = image + ((size_t)((2 * p + 1) * NSZ + iy)) * NSZ;

    float2 y8[8];
    {
        int ix0 = t + 128, ix1 = t + 192, ix6 = t, ix7 = t + 64;
        float w0 = ay * apod(ix0), w1 = ay * apod(ix1);
        float w6 = ay * apod(ix6), w7 = ay * apod(ix7);
        float2 x0 = make_float2(irow0[ix0] * w0, irow1[ix0] * w0);
        float2 x1 = make_float2(irow0[ix1] * w1, irow1[ix1] * w1);
        float2 x6 = make_float2(irow0[ix6] * w6, irow1[ix6] * w6);
        float2 x7 = make_float2(irow0[ix7] * w7, irow1[ix7] * w7);
        dft8_pruned(x0, x1, x6, x7, y8);
        twiddle8<0>(t, y8);
    }
    float2* A  = sm[0][r];
    float2* Bf = sm[1][r];
    #pragma unroll
    for (int q = 0; q < 8; ++q) A[PADIDX((t << 3) + q)] = y8[q];
    __syncthreads();
    {
        float2 x[8];
        #pragma unroll
        for (int pp = 0; pp < 8; ++pp) x[pp] = A[PADIDX(t + (pp << 6))];
        dft8(x, y8);
        twiddle8<1>(t, y8);
        int j = t >> 3, k = t & 7, base = k + (j << 6);
        #pragma unroll
        for (int q = 0; q < 8; ++q) Bf[PADIDX(base + (q << 3))] = y8[q];
    }
    __syncthreads();
    {
        float2 x[8];
        #pragma unroll
        for (int pp = 0; pp < 8; ++pp) x[pp] = Bf[PADIDX(t + (pp << 6))];
        dft8(x, y8);
        float2* Trow = T + (((size_t)(p << 8) + rp) << 9);
        #pragma unroll
        for (int q = 0; q < 8; ++q) Trow[t + (q << 6)] = y8[q];
    }
}

// ---------------------------------------------------------------- pass 2
// Batch-pair packed column FFT + Hermitian unpack (r9, verified).
__global__ __launch_bounds__(256) void pass2_colfft(const float2* __restrict__ T,
                                                    float2* __restrict__ kgrid) {
    __shared__ float2 B[8][578];
    int tid = threadIdx.x;
    int blk = blockIdx.x;
    int p = blk & 3;                                // batch pair
    int g = blk >> 2;                               // 0..63 col group
    const float2* Tb = T + ((size_t)p << 17);       // 256*512 per pair
    float2* Kb0 = kgrid + ((size_t)(2 * p) << 18);
    float2* Kb1 = Kb0 + ((size_t)1 << 18);

    #define COLG(c) ((g > 0) ? (((c) < 4) ? ((g << 2) + (c)) : (505 - (g << 2) + (c))) \
                             : (((c) < 4) ? (c) : (((c) == 7) ? 256 : (505 + (c)))))

    {
        int c = tid & 7, r0 = tid >> 3;             // r0 0..31
        int colg = COLG(c);
        #pragma unroll
        for (int k = 0; k < 8; ++k) {
            int rr = r0 + (k << 5);
            B[c][PADIDX(rr)] = Tb[((size_t)rr << 9) + colg];
        }
    }
    __syncthreads();
    int t = tid & 63;
    int c0 = tid >> 6;                              // slots c0 and c0+4
    float2* Ba = B[c0];
    float2* Bb = B[c0 + 4];
    float2 ya[8], yb[8];
    {
        float2 a0 = Ba[PADIDX(t)],       a1 = Ba[PADIDX(t + 64)];
        float2 a6 = Ba[PADIDX(t + 128)], a7 = Ba[PADIDX(t + 192)];
        float2 b0 = Bb[PADIDX(t)],       b1 = Bb[PADIDX(t + 64)];
        float2 b6 = Bb[PADIDX(t + 128)], b7 = Bb[PADIDX(t + 192)];
        dft8_pruned(a0, a1, a6, a7, ya); twiddle8<0>(t, ya);
        dft8_pruned(b0, b1, b6, b7, yb); twiddle8<0>(t, yb);
    }
    __syncthreads();
    #pragma unroll
    for (int q = 0; q < 8; ++q) {
        Ba[PADIDX((t << 3) + q)] = ya[q];
        Bb[PADIDX((t << 3) + q)] = yb[q];
    }
    __syncthreads();
    {
        float2 xa[8], xb[8];
        #pragma unroll
        for (int pp = 0; pp < 8; ++pp) { xa[pp] = Ba[PADIDX(t + (pp << 6))]; xb[pp] = Bb[PADIDX(t + (pp << 6))]; }
        dft8(xa, ya); twiddle8<1>(t, ya);
        dft8(xb, yb); twiddle8<1>(t, yb);
    }
    __syncthreads();
    {
        int j = t >> 3, k = t & 7, base = k + (j << 6);
        #pragma unroll
        for (int q = 0; q < 8; ++q) {
            Ba[PADIDX(base + (q << 3))] = ya[q];
            Bb[PADIDX(base + (q << 3))] = yb[q];
        }
    }
    __syncthreads();
    {
        float2 xa[8], xb[8];
        #pragma unroll
        for (int pp = 0; pp < 8; ++pp) { xa[pp] = Ba[PADIDX(t + (pp << 6))]; xb[pp] = Bb[PADIDX(t + (pp << 6))]; }
        dft8(xa, ya);
        dft8(xb, yb);
    }
    __syncthreads();
    #pragma unroll
    for (int q = 0; q < 8; ++q) {
        Ba[PADIDX(t + (q << 6))] = ya[q];
        Bb[PADIDX(t + (q << 6))] = yb[q];
    }
    __syncthreads();
    {
        int c = tid & 7, r0 = tid >> 3;
        int colg = COLG(c);
        int mc = 7 - c;
        if (g == 0) { if (c == 0) mc = 0; else if (c == 7) mc = 7; }
        #pragma unroll
        for (int k = 0; k < 16; ++k) {
            int rr = r0 + (k << 5);
            int mr = (512 - rr) & 511;
            float2 Z = B[c][PADIDX(rr)];
            float2 M = B[mc][PADIDX(mr)];
            float2 K0 = make_float2(0.5f * (Z.x + M.x), 0.5f * (Z.y - M.y));
            float2 K1 = make_float2(0.5f * (Z.y + M.y), 0.5f * (M.x - Z.x));
            size_t off = ((size_t)rr << 9) + colg;
            Kb0[off] = K0;
            Kb1[off] = K1;
        }
    }
    #undef COLG
}

// ---------------------------------------------------------------- pass 3
// Quad-cooperative KB gather, 2-deep software pipeline:
//  - all 24 ktraj/dcf scalars hoisted to the prologue (cold HBM latency
//    fully amortized; address-gen never stalls on a stream load)
//  - two named float4[6] gather buffers; buffer for iteration it+2 is
//    issued right after buffer it is consumed, so every gather has
//    >1 full phase (weights+fma of the other buffer) in flight before
//    its vmcnt wait — L2 latency hidden by construction
//  - float4 (16B-aligned: cpair is even) → global_load_dwordx4
//  - nontemporal hints on streams so they don't evict the kgrid L2 slab
__global__ __launch_bounds__(256) void interp_kb(const float* __restrict__ ktraj,
                                                 const float* __restrict__ dcf,
                                                 const float2* __restrict__ kgrid,
                                                 float* __restrict__ out) {
    int tid = threadIdx.x;
    int blk = blockIdx.x;
    int b = blk & 7;                          // XCD affinity
    int gb = blk >> 3;                        // 0..255
    int j = tid & 3;                          // lane within quad
    int q = tid >> 2;                         // quad in block 0..63
    int j2 = j << 1;

    const float SCALE = (float)GSZ / (2.0f * PI_F);
    const float* Kf = (const float*)(kgrid + ((size_t)b << 18));
    const float* kt1 = ktraj + ((size_t)(b * 2)) * MPTS;
    const float* kt2 = kt1 + MPTS;
    const float* dcfb = dcf + ((size_t)b << 17);
    float* out_re = out + ((size_t)b << 17);
    float* out_im = out_re + (size_t)NBATCH * MPTS;

    int m0 = (gb << 9) + q;                   // block covers 512 points

    // ---- prologue: all 8 iterations' stream scalars issued at once
    float r1[8], r2[8], rd[8];
    #pragma unroll
    for (int it = 0; it < 8; ++it) {
        int mm = m0 + (it << 6);
        r1[it] = __builtin_nontemporal_load(&kt1[mm]);
        r2[it] = __builtin_nontemporal_load(&kt2[mm]);
        rd[it] = __builtin_nontemporal_load(&dcfb[mm]);
    }

    // issue: compute indices from (tm1,tm2), fire 6 dwordx4 gathers into v
    auto issue = [&](float tm1, float tm2, float4* v, float& f1s, int& e0s) {
        float f1 = floorf(tm1), f2 = floorf(tm2);
        int if1 = (int)f1, if2 = (int)f2;
        int e0 = (if2 - 2) & ~1;              // even base col
        int cpair = (e0 + j2) & 511;          // even → pair never wraps mid
        #pragma unroll
        for (int a = 0; a < 6; ++a) {
            int rowb = (if1 + a - 2) & 511;
            v[a] = *reinterpret_cast<const float4*>(Kf + ((rowb << 10) + (cpair << 1)));
        }
        f1s = f1; e0s = e0;
    };

    // consume: weight math (no load dependency) + fma chain + quad reduce
    auto consume = [&](float tm1, float tm2, float f1, int e0, const float4* v,
                       float dd, int m) {
        float u2 = tm2 - (float)(e0 + j2);
        float w2a = kbw(u2);
        float w2b = kbw(u2 - 1.0f);
        float fr1 = tm1 - f1;
        float w1A = kbw(fr1 - (float)(j - 2));
        float w1B = kbw(fr1 - (float)(j + 2));
        float w1_[6];
        w1_[0] = qdpp<0x00>(w1A);
        w1_[1] = qdpp<0x55>(w1A);
        w1_[2] = qdpp<0xAA>(w1A);
        w1_[3] = qdpp<0xFF>(w1A);
        w1_[4] = qdpp<0x00>(w1B);
        w1_[5] = qdpp<0x55>(w1B);

        float c0re = 0.f, c0im = 0.f, c1re = 0.f, c1im = 0.f;
        #pragma unroll
        for (int a = 0; a < 6; ++a) {
            c0re = fmaf(w1_[a], v[a].x, c0re); c0im = fmaf(w1_[a], v[a].y, c0im);
            c1re = fmaf(w1_[a], v[a].z, c1re); c1im = fmaf(w1_[a], v[a].w, c1im);
        }
        float p_re = fmaf(w2a, c0re, w2b * c1re);
        float p_im = fmaf(w2a, c0im, w2b * c1im);
        p_re += qdpp<0xB1>(p_re);  p_re += qdpp<0x4E>(p_re);
        p_im += qdpp<0xB1>(p_im);  p_im += qdpp<0x4E>(p_im);

        if (j == 0) __builtin_nontemporal_store(p_re * dd, &out_re[m]);
        if (j == 1) __builtin_nontemporal_store(p_im * dd, &out_im[m]);
    };

    // ---- pipeline prologue: buffers for it=0 and it=1 in flight
    float4 vA[6], vB[6];
    float f1A, f1B; int e0A, e0B;
    float t1A = r1[0] * SCALE, t2A = r2[0] * SCALE;
    float t1B = r1[1] * SCALE, t2B = r2[1] * SCALE;
    issue(t1A, t2A, vA, f1A, e0A);
    issue(t1B, t2B, vB, f1B, e0B);

    // ---- steady state: consume(it) then immediately re-issue it+2
    #pragma unroll
    for (int k = 0; k < 4; ++k) {
        int itA = 2 * k, itB = 2 * k + 1;
        // phase A
        consume(t1A, t2A, f1A, e0A, vA, rd[itA], m0 + (itA << 6));
        if (k < 3) {
            t1A = r1[itA + 2] * SCALE; t2A = r2[itA + 2] * SCALE;
            issue(t1A, t2A, vA, f1A, e0A);
        }
        // phase B
        consume(t1B, t2B, f1B, e0B, vB, rd[itB], m0 + (itB << 6));
        if (k < 3) {
            t1B = r1[itB + 2] * SCALE; t2B = r2[itB + 2] * SCALE;
            issue(t1B, t2B, vB, f1B, e0B);
        }
    }
}

// ---------------------------------------------------------------- launch

extern "C" void kernel_launch(void* const* d_in, const int* in_sizes, int n_in,
                              void* d_out, int out_size, void* d_ws, size_t ws_size,
                              hipStream_t stream) {
    const float* image = (const float*)d_in[0];   // (8,256,256) f32
    const float* ktraj = (const float*)d_in[1];   // (8,2,131072) f32
    const float* dcf   = (const float*)d_in[2];   // (8,131072) f32
    float* out = (float*)d_out;                   // (2,8,131072) f32

    float2* T     = (float2*)d_ws;                        // 4 pairs *256*512 c64 = 4.2 MB
    float2* kgrid = T + (size_t)4 * 256 * GSZ;            // 8*512*512 c64 = 16.8 MB

    pass1_rowfft<<<512, 128, 0, stream>>>(image, T);      // 4 pairs * 256 rows / 2 per block
    pass2_colfft<<<256, 256, 0, stream>>>(T, kgrid);      // 4 pairs * 512 cols / 8 per block
    interp_kb<<<NBATCH * 256, 256, 0, stream>>>(ktraj, dcf, kgrid, out);
}

// Round 3
// 127.773 us; speedup vs baseline: 1.0342x; 1.0342x over previous
//
#include <hip/hip_runtime.h>
#include <math.h>

#define GSZ 512
#define NSZ 256
#define NBATCH 8
#define MPTS 131072
#define PI_F 3.14159265358979f
#define BETA_F 13.8551004f
#define BETA2_F (BETA_F * BETA_F)
#define RSQ2 0.70710678f
// LDS pad: +1 float2 every 8 → strided radix-8 access conflict-reduced
#define PADIDX(i) ((i) + ((i) >> 3))

typedef float f32x4 __attribute__((ext_vector_type(4)));

// All VMEM in pass 3 is inline asm: the compiler tracks zero memory ops,
// emits no waitcnt of its own, and cannot sink/merge/reorder the pipeline.
#define GLOAD4(dst, ptr) asm volatile("global_load_dwordx4 %0, %1, off" : "=&v"(dst) : "v"(ptr) : "memory")
#define GLOAD1(dst, ptr) asm volatile("global_load_dword %0, %1, off"   : "=&v"(dst) : "v"(ptr) : "memory")
#define GSTORE1(val, ptr) asm volatile("global_store_dword %0, %1, off" :: "v"(ptr), "v"(val) : "memory")
#define WAITVM(n) do { asm volatile("s_waitcnt vmcnt(" #n ")" ::: "memory"); \
                       __builtin_amdgcn_sched_barrier(0); } while (0)
#define SBAR() __builtin_amdgcn_sched_barrier(0)

// ---------------------------------------------------------------- helpers

__device__ __forceinline__ float apod(int i) {
    float x = (float)(i - 128);
    float arg = PI_F * 6.0f * x * (1.0f / 512.0f);
    float t = BETA2_F - arg * arg;
    float st = sqrtf(t);
    return st / sinhf(st);
}

// Branchless Kaiser-Bessel weight, large-x asymptotic i0 (3 transcendentals).
__device__ __forceinline__ float kbw(float u) {
    float t = 1.0f - u * u * (1.0f / 9.0f);
    float x = BETA_F * sqrtf(fmaxf(t, 0.0f));
    float xc = fmaxf(x, 0.35f);
    float R = __builtin_amdgcn_rsqf(xc);
    float R2 = R * R;
    float q = R * (0.39894228f + R2 * (0.04986779f + R2 * 0.02804702f));
    float w = __expf(xc) * q;
    return (t > 0.0f) ? w : 0.0f;
}

// DPP quad_perm cross-lane (no DS pipe)
template<int CTRL>
__device__ __forceinline__ float qdpp(float v) {
    int r = __builtin_amdgcn_mov_dpp(__float_as_int(v), CTRL, 0xF, 0xF, true);
    return __int_as_float(r);
}

__device__ __forceinline__ float2 cadd(float2 a, float2 b){ return make_float2(a.x+b.x, a.y+b.y); }
__device__ __forceinline__ float2 csub(float2 a, float2 b){ return make_float2(a.x-b.x, a.y-b.y); }
__device__ __forceinline__ float2 cmul(float2 a, float2 b){ return make_float2(a.x*b.x-a.y*b.y, a.x*b.y+a.y*b.x); }
__device__ __forceinline__ float2 mul_negi(float2 a){ return make_float2(a.y, -a.x); }
__device__ __forceinline__ float2 mul_posi(float2 a){ return make_float2(-a.y, a.x); }
__device__ __forceinline__ float2 mul_w81(float2 a){ return make_float2(RSQ2*(a.x+a.y), RSQ2*(a.y-a.x)); }
__device__ __forceinline__ float2 mul_w83(float2 a){ return make_float2(RSQ2*(a.y-a.x), -RSQ2*(a.x+a.y)); }

__device__ __forceinline__ void dft8_combine(float2 E0, float2 E1, float2 E2, float2 E3,
                                             float2 O0, float2 O1, float2 O2, float2 O3,
                                             float2* y) {
    float2 c1 = mul_w81(O1), c2 = mul_negi(O2), c3 = mul_w83(O3);
    y[0] = cadd(E0, O0); y[4] = csub(E0, O0);
    y[1] = cadd(E1, c1); y[5] = csub(E1, c1);
    y[2] = cadd(E2, c2); y[6] = csub(E2, c2);
    y[3] = cadd(E3, c3); y[7] = csub(E3, c3);
}

__device__ __forceinline__ void dft8(const float2* x, float2* y) {
    float2 a0=x[0], a1=x[2], a2=x[4], a3=x[6];
    float2 b0=x[1], b1=x[3], b2=x[5], b3=x[7];
    float2 ta0=cadd(a0,a2), ta1=csub(a0,a2), ta2=cadd(a1,a3), ta3=csub(a1,a3);
    float2 E0=cadd(ta0,ta2), E2=csub(ta0,ta2);
    float2 E1=cadd(ta1, mul_negi(ta3)), E3=cadd(ta1, mul_posi(ta3));
    float2 tb0=cadd(b0,b2), tb1=csub(b0,b2), tb2=cadd(b1,b3), tb3=csub(b1,b3);
    float2 O0=cadd(tb0,tb2), O2=csub(tb0,tb2);
    float2 O1=cadd(tb1, mul_negi(tb3)), O3=cadd(tb1, mul_posi(tb3));
    dft8_combine(E0,E1,E2,E3,O0,O1,O2,O3,y);
}

__device__ __forceinline__ void dft8_pruned(float2 x0, float2 x1, float2 x6, float2 x7, float2* y) {
    float2 E0 = cadd(x0, x6), E2 = csub(x0, x6);
    float2 E1 = cadd(x0, mul_posi(x6)), E3 = cadd(x0, mul_negi(x6));
    float2 O0 = cadd(x1, x7), O2 = csub(x1, x7);
    float2 O1 = cadd(x1, mul_posi(x7)), O3 = cadd(x1, mul_negi(x7));
    dft8_combine(E0,E1,E2,E3,O0,O1,O2,O3,y);
}

template<int S>
__device__ __forceinline__ void twiddle8(int t, float2* y) {
    if (S < 2) {
        int j = (S == 0) ? t : (t >> 3);
        const float scale = (S == 0) ? (-2.0f*PI_F/512.0f) : (-2.0f*PI_F/64.0f);
        float theta = scale * (float)j;
        float sn, cs;
        __sincosf(theta, &sn, &cs);              // sin FIRST, cos second
        float2 w = make_float2(cs, sn), wq = w;
        y[1] = cmul(y[1], wq);
        #pragma unroll
        for (int q = 2; q < 8; ++q) { wq = cmul(wq, w); y[q] = cmul(y[q], wq); }
    }
}

// ---------------------------------------------------------------- pass 1
// Batch-pair packed row FFT (r9): z = img_{2p} + i*img_{2p+1}. 2 rows/block.
__global__ __launch_bounds__(128) void pass1_rowfft(const float* __restrict__ image,
                                                    float2* __restrict__ T) {
    __shared__ float2 sm[2][2][578];
    int tid = threadIdx.x;
    int r = tid >> 6, t = tid & 63;                 // r in {0,1}
    int blk = blockIdx.x;
    int p = blk & 3;                                // batch pair 0..3
    int g = blk >> 2;                               // 0..127
    int rp = (g << 1) + r;                          // compact row 0..255
    int y = (rp < 128) ? rp : (rp + 256);
    int iy = (y < 128) ? (y + 128) : (y - 384);
    float ay = apod(iy);
    const float* irow0 = image + ((size_t)((2 * p)     * NSZ + iy)) * NSZ;
    const float* irow1 = image + ((size_t)((2 * p + 1) * NSZ + iy)) * NSZ;

    float2 y8[8];
    {
        int ix0 = t + 128, ix1 = t + 192, ix6 = t, ix7 = t + 64;
        float w0 = ay * apod(ix0), w1 = ay * apod(ix1);
        float w6 = ay * apod(ix6), w7 = ay * apod(ix7);
        float2 x0 = make_float2(irow0[ix0] * w0, irow1[ix0] * w0);
        float2 x1 = make_float2(irow0[ix1] * w1, irow1[ix1] * w1);
        float2 x6 = make_float2(irow0[ix6] * w6, irow1[ix6] * w6);
        float2 x7 = make_float2(irow0[ix7] * w7, irow1[ix7] * w7);
        dft8_pruned(x0, x1, x6, x7, y8);
        twiddle8<0>(t, y8);
    }
    float2* A  = sm[0][r];
    float2* Bf = sm[1][r];
    #pragma unroll
    for (int q = 0; q < 8; ++q) A[PADIDX((t << 3) + q)] = y8[q];
    __syncthreads();
    {
        float2 x[8];
        #pragma unroll
        for (int pp = 0; pp < 8; ++pp) x[pp] = A[PADIDX(t + (pp << 6))];
        dft8(x, y8);
        twiddle8<1>(t, y8);
        int j = t >> 3, k = t & 7, base = k + (j << 6);
        #pragma unroll
        for (int q = 0; q < 8; ++q) Bf[PADIDX(base + (q << 3))] = y8[q];
    }
    __syncthreads();
    {
        float2 x[8];
        #pragma unroll
        for (int pp = 0; pp < 8; ++pp) x[pp] = Bf[PADIDX(t + (pp << 6))];
        dft8(x, y8);
        float2* Trow = T + (((size_t)(p << 8) + rp) << 9);
        #pragma unroll
        for (int q = 0; q < 8; ++q) Trow[t + (q << 6)] = y8[q];
    }
}

// ---------------------------------------------------------------- pass 2
// Batch-pair packed column FFT + Hermitian unpack (r9, verified).
__global__ __launch_bounds__(256) void pass2_colfft(const float2* __restrict__ T,
                                                    float2* __restrict__ kgrid) {
    __shared__ float2 B[8][578];
    int tid = threadIdx.x;
    int blk = blockIdx.x;
    int p = blk & 3;                                // batch pair
    int g = blk >> 2;                               // 0..63 col group
    const float2* Tb = T + ((size_t)p << 17);       // 256*512 per pair
    float2* Kb0 = kgrid + ((size_t)(2 * p) << 18);
    float2* Kb1 = Kb0 + ((size_t)1 << 18);

    #define COLG(c) ((g > 0) ? (((c) < 4) ? ((g << 2) + (c)) : (505 - (g << 2) + (c))) \
                             : (((c) < 4) ? (c) : (((c) == 7) ? 256 : (505 + (c)))))

    {
        int c = tid & 7, r0 = tid >> 3;             // r0 0..31
        int colg = COLG(c);
        #pragma unroll
        for (int k = 0; k < 8; ++k) {
            int rr = r0 + (k << 5);
            B[c][PADIDX(rr)] = Tb[((size_t)rr << 9) + colg];
        }
    }
    __syncthreads();
    int t = tid & 63;
    int c0 = tid >> 6;                              // slots c0 and c0+4
    float2* Ba = B[c0];
    float2* Bb = B[c0 + 4];
    float2 ya[8], yb[8];
    {
        float2 a0 = Ba[PADIDX(t)],       a1 = Ba[PADIDX(t + 64)];
        float2 a6 = Ba[PADIDX(t + 128)], a7 = Ba[PADIDX(t + 192)];
        float2 b0 = Bb[PADIDX(t)],       b1 = Bb[PADIDX(t + 64)];
        float2 b6 = Bb[PADIDX(t + 128)], b7 = Bb[PADIDX(t + 192)];
        dft8_pruned(a0, a1, a6, a7, ya); twiddle8<0>(t, ya);
        dft8_pruned(b0, b1, b6, b7, yb); twiddle8<0>(t, yb);
    }
    __syncthreads();
    #pragma unroll
    for (int q = 0; q < 8; ++q) {
        Ba[PADIDX((t << 3) + q)] = ya[q];
        Bb[PADIDX((t << 3) + q)] = yb[q];
    }
    __syncthreads();
    {
        float2 xa[8], xb[8];
        #pragma unroll
        for (int pp = 0; pp < 8; ++pp) { xa[pp] = Ba[PADIDX(t + (pp << 6))]; xb[pp] = Bb[PADIDX(t + (pp << 6))]; }
        dft8(xa, ya); twiddle8<1>(t, ya);
        dft8(xb, yb); twiddle8<1>(t, yb);
    }
    __syncthreads();
    {
        int j = t >> 3, k = t & 7, base = k + (j << 6);
        #pragma unroll
        for (int q = 0; q < 8; ++q) {
            Ba[PADIDX(base + (q << 3))] = ya[q];
            Bb[PADIDX(base + (q << 3))] = yb[q];
        }
    }
    __syncthreads();
    {
        float2 xa[8], xb[8];
        #pragma unroll
        for (int pp = 0; pp < 8; ++pp) { xa[pp] = Ba[PADIDX(t + (pp << 6))]; xb[pp] = Bb[PADIDX(t + (pp << 6))]; }
        dft8(xa, ya);
        dft8(xb, yb);
    }
    __syncthreads();
    #pragma unroll
    for (int q = 0; q < 8; ++q) {
        Ba[PADIDX(t + (q << 6))] = ya[q];
        Bb[PADIDX(t + (q << 6))] = yb[q];
    }
    __syncthreads();
    {
        int c = tid & 7, r0 = tid >> 3;
        int colg = COLG(c);
        int mc = 7 - c;
        if (g == 0) { if (c == 0) mc = 0; else if (c == 7) mc = 7; }
        #pragma unroll
        for (int k = 0; k < 16; ++k) {
            int rr = r0 + (k << 5);
            int mr = (512 - rr) & 511;
            float2 Z = B[c][PADIDX(rr)];
            float2 M = B[mc][PADIDX(mr)];
            float2 K0 = make_float2(0.5f * (Z.x + M.x), 0.5f * (Z.y - M.y));
            float2 K1 = make_float2(0.5f * (Z.y + M.y), 0.5f * (M.x - Z.x));
            size_t off = ((size_t)rr << 9) + colg;
            Kb0[off] = K0;
            Kb1[off] = K1;
        }
    }
    #undef COLG
}

// ---------------------------------------------------------------- pass 3
// Quad-cooperative KB gather, ISA-level pipeline, fully straight-line:
//  - 24 scalar asm loads + vmcnt(0) in prologue
//  - 12 named f32x4 buffers, 8 macro-expanded stages, 1-ahead issue
//  - per stage: ISSUE(i+1) → WEIGHTS(i) → vmcnt(6)+sched_barrier → FMA(i)
//    vmcnt(6) drains everything older than the 6 newest loads = current
//    buffer + prior stores, robust to exact interleave.
//  - stores are asm too: compiler sees zero memory ops, emits no waitcnt.

// per-point address/index precompute + 6 row gathers into named buffers
#define ISSUE(i, V0, V1, V2, V3, V4, V5) do {                               \
    float tm1 = r1v[i] * SCALE, tm2 = r2v[i] * SCALE;                       \
    float f1 = floorf(tm1), f2 = floorf(tm2);                               \
    int if1 = (int)f1, if2 = (int)f2;                                       \
    int e0 = (if2 - 2) & ~1;              /* even base col */               \
    int cpair = (e0 + j2) & 511;          /* even → pair never wraps mid */ \
    const float* pb = Kf + (cpair << 1);                                    \
    GLOAD4(V0, pb + (((if1 - 2) & 511) << 10));                             \
    GLOAD4(V1, pb + (((if1 - 1) & 511) << 10));                             \
    GLOAD4(V2, pb + (((if1    ) & 511) << 10));                             \
    GLOAD4(V3, pb + (((if1 + 1) & 511) << 10));                             \
    GLOAD4(V4, pb + (((if1 + 2) & 511) << 10));                             \
    GLOAD4(V5, pb + (((if1 + 3) & 511) << 10));                             \
    fr1v[i] = tm1 - f1;                                                     \
    u2v[i]  = tm2 - (float)(e0 + j2);                                       \
    SBAR();                                                                 \
} while (0)

// transcendental weight math — no dependency on the gather buffers
#define WEIGHTS(i)                                                          \
    float u2_##i  = u2v[i];                                                 \
    float w2a_##i = kbw(u2_##i);                                            \
    float w2b_##i = kbw(u2_##i - 1.0f);                                     \
    float w1A_##i = kbw(fr1v[i] - fjm2);                                    \
    float w1B_##i = kbw(fr1v[i] - fjp2);                                    \
    float w0_##i = qdpp<0x00>(w1A_##i);                                     \
    float w1_##i = qdpp<0x55>(w1A_##i);                                     \
    float w2_##i = qdpp<0xAA>(w1A_##i);                                     \
    float w3_##i = qdpp<0xFF>(w1A_##i);                                     \
    float w4_##i = qdpp<0x00>(w1B_##i);                                     \
    float w5_##i = qdpp<0x55>(w1B_##i);

// fma chain (bit-identical ordering to the verified r0 kernel) + reduce
#define FMACONS(i, V0, V1, V2, V3, V4, V5) do {                             \
    float c0re = w0_##i * V0.x, c0im = w0_##i * V0.y;                       \
    float c1re = w0_##i * V0.z, c1im = w0_##i * V0.w;                       \
    c0re = fmaf(w1_##i, V1.x, c0re); c0im = fmaf(w1_##i, V1.y, c0im);       \
    c1re = fmaf(w1_##i, V1.z, c1re); c1im = fmaf(w1_##i, V1.w, c1im);       \
    c0re = fmaf(w2_##i, V2.x, c0re); c0im = fmaf(w2_##i, V2.y, c0im);       \
    c1re = fmaf(w2_##i, V2.z, c1re); c1im = fmaf(w2_##i, V2.w, c1im);       \
    c0re = fmaf(w3_##i, V3.x, c0re); c0im = fmaf(w3_##i, V3.y, c0im);       \
    c1re = fmaf(w3_##i, V3.z, c1re); c1im = fmaf(w3_##i, V3.w, c1im);       \
    c0re = fmaf(w4_##i, V4.x, c0re); c0im = fmaf(w4_##i, V4.y, c0im);       \
    c1re = fmaf(w4_##i, V4.z, c1re); c1im = fmaf(w4_##i, V4.w, c1im);       \
    c0re = fmaf(w5_##i, V5.x, c0re); c0im = fmaf(w5_##i, V5.y, c0im);       \
    c1re = fmaf(w5_##i, V5.z, c1re); c1im = fmaf(w5_##i, V5.w, c1im);       \
    float p_re = fmaf(w2a_##i, c0re, w2b_##i * c1re);                       \
    float p_im = fmaf(w2a_##i, c0im, w2b_##i * c1im);                       \
    p_re += qdpp<0xB1>(p_re); p_re += qdpp<0x4E>(p_re);                     \
    p_im += qdpp<0xB1>(p_im); p_im += qdpp<0x4E>(p_im);                     \
    int mmm = m0 + ((i) << 6);                                              \
    float sre = p_re * rdv[i], sim = p_im * rdv[i];                         \
    if (j == 0) GSTORE1(sre, out_re + mmm);                                 \
    if (j == 1) GSTORE1(sim, out_im + mmm);                                 \
} while (0)

__global__ __launch_bounds__(256) void interp_kb(const float* __restrict__ ktraj,
                                                 const float* __restrict__ dcf,
                                                 const float2* __restrict__ kgrid,
                                                 float* __restrict__ out) {
    int tid = threadIdx.x;
    int blk = blockIdx.x;
    int b = blk & 7;                          // XCD affinity
    int gb = blk >> 3;                        // 0..255
    int j = tid & 3;                          // lane within quad
    int q = tid >> 2;                         // quad in block 0..63
    int j2 = j << 1;
    float fjm2 = (float)(j - 2), fjp2 = (float)(j + 2);

    const float SCALE = (float)GSZ / (2.0f * PI_F);
    const float* Kf = (const float*)(kgrid + ((size_t)b << 18));
    const float* kt1 = ktraj + ((size_t)(b * 2)) * MPTS;
    const float* kt2 = kt1 + MPTS;
    const float* dcfb = dcf + ((size_t)b << 17);
    float* out_re = out + ((size_t)b << 17);
    float* out_im = out_re + (size_t)NBATCH * MPTS;

    int m0 = (gb << 9) + q;                   // block covers 512 points

    // ---- prologue: 24 stream scalars via asm, one drain (static indices)
    float r1v[8], r2v[8], rdv[8];
    #define LOADPT(i) do {                     \
        GLOAD1(r1v[i], kt1 + m0 + ((i) << 6)); \
        GLOAD1(r2v[i], kt2 + m0 + ((i) << 6)); \
        GLOAD1(rdv[i], dcfb + m0 + ((i) << 6)); } while (0)
    LOADPT(0); LOADPT(1); LOADPT(2); LOADPT(3);
    LOADPT(4); LOADPT(5); LOADPT(6); LOADPT(7);
    #undef LOADPT
    WAITVM(0);

    float fr1v[8], u2v[8];
    f32x4 A0, A1, A2, A3, A4, A5;
    f32x4 B0, B1, B2, B3, B4, B5;

    ISSUE(0, A0, A1, A2, A3, A4, A5);
    ISSUE(1, B0, B1, B2, B3, B4, B5);

    // stage 0
    WEIGHTS(0);
    WAITVM(6);
    FMACONS(0, A0, A1, A2, A3, A4, A5);
    // stage 1
    ISSUE(2, A0, A1, A2, A3, A4, A5);
    WEIGHTS(1);
    WAITVM(6);
    FMACONS(1, B0, B1, B2, B3, B4, B5);
    // stage 2
    ISSUE(3, B0, B1, B2, B3, B4, B5);
    WEIGHTS(2);
    WAITVM(6);
    FMACONS(2, A0, A1, A2, A3, A4, A5);
    // stage 3
    ISSUE(4, A0, A1, A2, A3, A4, A5);
    WEIGHTS(3);
    WAITVM(6);
    FMACONS(3, B0, B1, B2, B3, B4, B5);
    // stage 4
    ISSUE(5, B0, B1, B2, B3, B4, B5);
    WEIGHTS(4);
    WAITVM(6);
    FMACONS(4, A0, A1, A2, A3, A4, A5);
    // stage 5
    ISSUE(6, A0, A1, A2, A3, A4, A5);
    WEIGHTS(5);
    WAITVM(6);
    FMACONS(5, B0, B1, B2, B3, B4, B5);
    // stage 6
    ISSUE(7, B0, B1, B2, B3, B4, B5);
    WEIGHTS(6);
    WAITVM(6);
    FMACONS(6, A0, A1, A2, A3, A4, A5);
    // stage 7
    WEIGHTS(7);
    WAITVM(0);
    FMACONS(7, B0, B1, B2, B3, B4, B5);

    WAITVM(0);  // drain stores before exit (defensive)
}

// ---------------------------------------------------------------- launch

extern "C" void kernel_launch(void* const* d_in, const int* in_sizes, int n_in,
                              void* d_out, int out_size, void* d_ws, size_t ws_size,
                              hipStream_t stream) {
    const float* image = (const float*)d_in[0];   // (8,256,256) f32
    const float* ktraj = (const float*)d_in[1];   // (8,2,131072) f32
    const float* dcf   = (const float*)d_in[2];   // (8,131072) f32
    float* out = (float*)d_out;                   // (2,8,131072) f32

    float2* T     = (float2*)d_ws;                        // 4 pairs *256*512 c64 = 4.2 MB
    float2* kgrid = T + (size_t)4 * 256 * GSZ;            // 8*512*512 c64 = 16.8 MB

    pass1_rowfft<<<512, 128, 0, stream>>>(image, T);      // 4 pairs * 256 rows / 2 per block
    pass2_colfft<<<256, 256, 0, stream>>>(T, kgrid);      // 4 pairs * 512 cols / 8 per block
    interp_kb<<<NBATCH * 256, 256, 0, stream>>>(ktraj, dcf, kgrid, out);
}

// Round 4
// 125.468 us; speedup vs baseline: 1.0532x; 1.0184x over previous
//
#include <hip/hip_runtime.h>
#include <math.h>

#define GSZ 512
#define NSZ 256
#define NBATCH 8
#define MPTS 131072
#define PI_F 3.14159265358979f
#define BETA_F 13.8551004f
#define BETA2_F (BETA_F * BETA_F)
#define RSQ2 0.70710678f
// LDS pad: +1 float2 every 8 → strided radix-8 access conflict-reduced
#define PADIDX(i) ((i) + ((i) >> 3))

typedef float f32x4 __attribute__((ext_vector_type(4)));

// All VMEM in pass 3 is inline asm: the compiler tracks zero memory ops,
// emits no waitcnt of its own, and cannot sink/merge/reorder the pipeline.
#define GLOAD4(dst, ptr) asm volatile("global_load_dwordx4 %0, %1, off" : "=&v"(dst) : "v"(ptr) : "memory")
#define GLOAD1(dst, ptr) asm volatile("global_load_dword %0, %1, off"   : "=&v"(dst) : "v"(ptr) : "memory")
#define GSTORE1(val, ptr) asm volatile("global_store_dword %0, %1, off" :: "v"(ptr), "v"(val) : "memory")
#define WAITVM(n) do { asm volatile("s_waitcnt vmcnt(" #n ")" ::: "memory"); \
                       __builtin_amdgcn_sched_barrier(0); } while (0)
#define SBAR() __builtin_amdgcn_sched_barrier(0)

// ---------------------------------------------------------------- helpers

// Exact asymptotic de-apodization: st ∈ [13.03, 13.855] so
// st/sinh(st) = 2·st·e^(−st)·(1+O(e^(−2st))), rel err < 5e-12.
__device__ __forceinline__ float apod(int i) {
    float x = (float)(i - 128);
    float arg = PI_F * 6.0f * x * (1.0f / 512.0f);
    float t = BETA2_F - arg * arg;
    float st = sqrtf(t);
    return 2.0f * st * __expf(-st);
}

// Branchless Kaiser-Bessel weight, large-x asymptotic i0 (3 transcendentals).
__device__ __forceinline__ float kbw(float u) {
    float t = 1.0f - u * u * (1.0f / 9.0f);
    float x = BETA_F * sqrtf(fmaxf(t, 0.0f));
    float xc = fmaxf(x, 0.35f);
    float R = __builtin_amdgcn_rsqf(xc);
    float R2 = R * R;
    float q = R * (0.39894228f + R2 * (0.04986779f + R2 * 0.02804702f));
    float w = __expf(xc) * q;
    return (t > 0.0f) ? w : 0.0f;
}

// DPP quad_perm cross-lane (no DS pipe)
template<int CTRL>
__device__ __forceinline__ float qdpp(float v) {
    int r = __builtin_amdgcn_mov_dpp(__float_as_int(v), CTRL, 0xF, 0xF, true);
    return __int_as_float(r);
}

__device__ __forceinline__ float2 cadd(float2 a, float2 b){ return make_float2(a.x+b.x, a.y+b.y); }
__device__ __forceinline__ float2 csub(float2 a, float2 b){ return make_float2(a.x-b.x, a.y-b.y); }
__device__ __forceinline__ float2 cmul(float2 a, float2 b){ return make_float2(a.x*b.x-a.y*b.y, a.x*b.y+a.y*b.x); }
__device__ __forceinline__ float2 mul_negi(float2 a){ return make_float2(a.y, -a.x); }
__device__ __forceinline__ float2 mul_posi(float2 a){ return make_float2(-a.y, a.x); }
__device__ __forceinline__ float2 mul_w81(float2 a){ return make_float2(RSQ2*(a.x+a.y), RSQ2*(a.y-a.x)); }
__device__ __forceinline__ float2 mul_w83(float2 a){ return make_float2(RSQ2*(a.y-a.x), -RSQ2*(a.x+a.y)); }

__device__ __forceinline__ void dft8_combine(float2 E0, float2 E1, float2 E2, float2 E3,
                                             float2 O0, float2 O1, float2 O2, float2 O3,
                                             float2* y) {
    float2 c1 = mul_w81(O1), c2 = mul_negi(O2), c3 = mul_w83(O3);
    y[0] = cadd(E0, O0); y[4] = csub(E0, O0);
    y[1] = cadd(E1, c1); y[5] = csub(E1, c1);
    y[2] = cadd(E2, c2); y[6] = csub(E2, c2);
    y[3] = cadd(E3, c3); y[7] = csub(E3, c3);
}

__device__ __forceinline__ void dft8(const float2* x, float2* y) {
    float2 a0=x[0], a1=x[2], a2=x[4], a3=x[6];
    float2 b0=x[1], b1=x[3], b2=x[5], b3=x[7];
    float2 ta0=cadd(a0,a2), ta1=csub(a0,a2), ta2=cadd(a1,a3), ta3=csub(a1,a3);
    float2 E0=cadd(ta0,ta2), E2=csub(ta0,ta2);
    float2 E1=cadd(ta1, mul_negi(ta3)), E3=cadd(ta1, mul_posi(ta3));
    float2 tb0=cadd(b0,b2), tb1=csub(b0,b2), tb2=cadd(b1,b3), tb3=csub(b1,b3);
    float2 O0=cadd(tb0,tb2), O2=csub(tb0,tb2);
    float2 O1=cadd(tb1, mul_negi(tb3)), O3=cadd(tb1, mul_posi(tb3));
    dft8_combine(E0,E1,E2,E3,O0,O1,O2,O3,y);
}

__device__ __forceinline__ void dft8_pruned(float2 x0, float2 x1, float2 x6, float2 x7, float2* y) {
    float2 E0 = cadd(x0, x6), E2 = csub(x0, x6);
    float2 E1 = cadd(x0, mul_posi(x6)), E3 = cadd(x0, mul_negi(x6));
    float2 O0 = cadd(x1, x7), O2 = csub(x1, x7);
    float2 O1 = cadd(x1, mul_posi(x7)), O3 = cadd(x1, mul_negi(x7));
    dft8_combine(E0,E1,E2,E3,O0,O1,O2,O3,y);
}

template<int S>
__device__ __forceinline__ void twiddle8(int t, float2* y) {
    if (S < 2) {
        int j = (S == 0) ? t : (t >> 3);
        const float scale = (S == 0) ? (-2.0f*PI_F/512.0f) : (-2.0f*PI_F/64.0f);
        float theta = scale * (float)j;
        float sn, cs;
        __sincosf(theta, &sn, &cs);              // sin FIRST, cos second
        float2 w = make_float2(cs, sn), wq = w;
        y[1] = cmul(y[1], wq);
        #pragma unroll
        for (int q = 2; q < 8; ++q) { wq = cmul(wq, w); y[q] = cmul(y[q], wq); }
    }
}

// ----- pair-cooperative half-butterfly primitives (pass 1, 128 thr/row) ---

// lane-pair swap: lane 2k <-> 2k+1 (quad_perm [1,0,3,2])
__device__ __forceinline__ float2 pswap(float2 v) {
    return make_float2(qdpp<0xB1>(v.x), qdpp<0xB1>(v.y));
}

// half of dft8's first two levels: identical formula for E-path (h=0,
// inputs x[0],x[2],x[4],x[6]) and O-path (h=1, inputs x[1],x[3],x[5],x[7]).
__device__ __forceinline__ void dft8_half(const float2* v, float2* EO) {
    float2 t0 = cadd(v[0], v[2]), t1 = csub(v[0], v[2]);
    float2 t2 = cadd(v[1], v[3]), t3 = csub(v[1], v[3]);
    EO[0] = cadd(t0, t2); EO[2] = csub(t0, t2);
    EO[1] = cadd(t1, mul_negi(t3)); EO[3] = cadd(t1, mul_posi(t3));
}

// pruned half: E from (x0,x6) [h=0], O from (x1,x7) [h=1] — same formula.
__device__ __forceinline__ void dft8p_half(float2 u0, float2 u1, float2* EO) {
    EO[0] = cadd(u0, u1); EO[2] = csub(u0, u1);
    EO[1] = cadd(u0, mul_posi(u1)); EO[3] = cadd(u0, mul_negi(u1));
}

// combine via DPP exchange: lane h=0 holds E0..3, h=1 holds O0..3.
// y_global[4h+qq]: h=0 -> E+c, h=1 -> E-c  (c0=O0, c1=w81*O1, c2=-i*O2, c3=w83*O3)
__device__ __forceinline__ void combine_half(int h, const float2* V, float2* y) {
    float2 P0 = pswap(V[0]), P1 = pswap(V[1]), P2 = pswap(V[2]), P3 = pswap(V[3]);
    float2 E0 = h ? P0 : V[0], O0 = h ? V[0] : P0;
    float2 E1 = h ? P1 : V[1], O1 = h ? V[1] : P1;
    float2 E2 = h ? P2 : V[2], O2 = h ? V[2] : P2;
    float2 E3 = h ? P3 : V[3], O3 = h ? V[3] : P3;
    float2 c1 = mul_w81(O1), c2 = mul_negi(O2), c3 = mul_w83(O3);
    float s = h ? -1.0f : 1.0f;
    y[0] = make_float2(fmaf(s, O0.x, E0.x), fmaf(s, O0.y, E0.y));
    y[1] = make_float2(fmaf(s, c1.x, E1.x), fmaf(s, c1.y, E1.y));
    y[2] = make_float2(fmaf(s, c2.x, E2.x), fmaf(s, c2.y, E2.y));
    y[3] = make_float2(fmaf(s, c3.x, E3.x), fmaf(s, c3.y, E3.y));
}

// y_local[qq] *= w^(4h+qq), w = e^{i*scale*j}. Branchless h-select.
__device__ __forceinline__ void twiddle4h(int jidx, float scale, int h, float2* y) {
    float theta = scale * (float)jidx;
    float sn, cs;
    __sincosf(theta, &sn, &cs);                  // sin FIRST, cos second
    float2 w = make_float2(cs, sn);
    float2 w2 = cmul(w, w);
    float2 w4 = cmul(w2, w2);
    float2 m = h ? w4 : make_float2(1.0f, 0.0f);
    y[0] = cmul(y[0], m);
    float2 wq = cmul(m, w); y[1] = cmul(y[1], wq);
    wq = cmul(wq, w);       y[2] = cmul(y[2], wq);
    wq = cmul(wq, w);       y[3] = cmul(y[3], wq);
}

// ---------------------------------------------------------------- pass 1
// Pair-cooperative row FFT: 128 threads per 512-pt FFT (2 waves/row-FFT is
// now 1 row per 2 half-waves): thread owns 4 elements = one half (E or O)
// of a radix-8 butterfly; adjacent lanes h=0/1 pair via DPP quad_perm.
// 2048 waves total = 2 waves/SIMD (was 1) — double latency hiding, half
// the per-wave chain. Stage/twiddle/index conventions identical to the
// verified radix-8 kernel.
__global__ __launch_bounds__(256) void pass1_rowfft(const float* __restrict__ image,
                                                    float2* __restrict__ T) {
    __shared__ float2 sm[2][2][578];
    int tid = threadIdx.x;
    int r = tid >> 7;                               // row within block {0,1}
    int tt = tid & 127;
    int h = tt & 1;                                 // butterfly half (E/O)
    int b = tt >> 1;                                // butterfly index 0..63
    int blk = blockIdx.x;
    int p = blk & 3;                                // batch pair 0..3
    int g = blk >> 2;                               // 0..127
    int rp = (g << 1) + r;                          // compact row 0..255
    int y = (rp < 128) ? rp : (rp + 256);
    int iy = (y < 128) ? (y + 128) : (y - 384);
    float ay = apod(iy);
    const float* irow0 = image + ((size_t)((2 * p)     * NSZ + iy)) * NSZ;
    const float* irow1 = image + ((size_t)((2 * p + 1) * NSZ + iy)) * NSZ;

    float2 y4[4];
    {
        // h=0: (x0@b+128, x6@b) -> E ; h=1: (x1@b+192, x7@b+64) -> O
        int iA = h ? (b + 192) : (b + 128);
        int iB = h ? (b + 64)  : b;
        float wA = ay * apod(iA), wB = ay * apod(iB);
        float2 u0 = make_float2(irow0[iA] * wA, irow1[iA] * wA);
        float2 u1 = make_float2(irow0[iB] * wB, irow1[iB] * wB);
        float2 EO[4];
        dft8p_half(u0, u1, EO);
        combine_half(h, EO, y4);
        twiddle4h(b, -2.0f * PI_F / 512.0f, h, y4);
    }
    float2* A  = sm[0][r];
    float2* Bf = sm[1][r];
    #pragma unroll
    for (int qq = 0; qq < 4; ++qq) A[PADIDX((b << 3) + (h << 2) + qq)] = y4[qq];
    __syncthreads();
    {
        float2 v[4];
        #pragma unroll
        for (int i = 0; i < 4; ++i) v[i] = A[PADIDX(b + (((i << 1) + h) << 6))];
        float2 EO[4];
        dft8_half(v, EO);
        combine_half(h, EO, y4);
        twiddle4h(b >> 3, -2.0f * PI_F / 64.0f, h, y4);
        int base = (b & 7) + ((b >> 3) << 6);
        #pragma unroll
        for (int qq = 0; qq < 4; ++qq) Bf[PADIDX(base + (((h << 2) + qq) << 3))] = y4[qq];
    }
    __syncthreads();
    {
        float2 v[4];
        #pragma unroll
        for (int i = 0; i < 4; ++i) v[i] = Bf[PADIDX(b + (((i << 1) + h) << 6))];
        float2 EO[4];
        dft8_half(v, EO);
        combine_half(h, EO, y4);
        float2* Trow = T + (((size_t)(p << 8) + rp) << 9);
        #pragma unroll
        for (int qq = 0; qq < 4; ++qq) Trow[b + (((h << 2) + qq) << 6)] = y4[qq];
    }
}

// ---------------------------------------------------------------- pass 2
// Batch-pair packed column FFT + Hermitian unpack (r9, verified).
__global__ __launch_bounds__(256) void pass2_colfft(const float2* __restrict__ T,
                                                    float2* __restrict__ kgrid) {
    __shared__ float2 B[8][578];
    int tid = threadIdx.x;
    int blk = blockIdx.x;
    int p = blk & 3;                                // batch pair
    int g = blk >> 2;                               // 0..63 col group
    const float2* Tb = T + ((size_t)p << 17);       // 256*512 per pair
    float2* Kb0 = kgrid + ((size_t)(2 * p) << 18);
    float2* Kb1 = Kb0 + ((size_t)1 << 18);

    #define COLG(c) ((g > 0) ? (((c) < 4) ? ((g << 2) + (c)) : (505 - (g << 2) + (c))) \
                             : (((c) < 4) ? (c) : (((c) == 7) ? 256 : (505 + (c)))))

    {
        int c = tid & 7, r0 = tid >> 3;             // r0 0..31
        int colg = COLG(c);
        #pragma unroll
        for (int k = 0; k < 8; ++k) {
            int rr = r0 + (k << 5);
            B[c][PADIDX(rr)] = Tb[((size_t)rr << 9) + colg];
        }
    }
    __syncthreads();
    int t = tid & 63;
    int c0 = tid >> 6;                              // slots c0 and c0+4
    float2* Ba = B[c0];
    float2* Bb = B[c0 + 4];
    float2 ya[8], yb[8];
    {
        float2 a0 = Ba[PADIDX(t)],       a1 = Ba[PADIDX(t + 64)];
        float2 a6 = Ba[PADIDX(t + 128)], a7 = Ba[PADIDX(t + 192)];
        float2 b0 = Bb[PADIDX(t)],       b1 = Bb[PADIDX(t + 64)];
        float2 b6 = Bb[PADIDX(t + 128)], b7 = Bb[PADIDX(t + 192)];
        dft8_pruned(a0, a1, a6, a7, ya); twiddle8<0>(t, ya);
        dft8_pruned(b0, b1, b6, b7, yb); twiddle8<0>(t, yb);
    }
    __syncthreads();
    #pragma unroll
    for (int q = 0; q < 8; ++q) {
        Ba[PADIDX((t << 3) + q)] = ya[q];
        Bb[PADIDX((t << 3) + q)] = yb[q];
    }
    __syncthreads();
    {
        float2 xa[8], xb[8];
        #pragma unroll
        for (int pp = 0; pp < 8; ++pp) { xa[pp] = Ba[PADIDX(t + (pp << 6))]; xb[pp] = Bb[PADIDX(t + (pp << 6))]; }
        dft8(xa, ya); twiddle8<1>(t, ya);
        dft8(xb, yb); twiddle8<1>(t, yb);
    }
    __syncthreads();
    {
        int j = t >> 3, k = t & 7, base = k + (j << 6);
        #pragma unroll
        for (int q = 0; q < 8; ++q) {
            Ba[PADIDX(base + (q << 3))] = ya[q];
            Bb[PADIDX(base + (q << 3))] = yb[q];
        }
    }
    __syncthreads();
    {
        float2 xa[8], xb[8];
        #pragma unroll
        for (int pp = 0; pp < 8; ++pp) { xa[pp] = Ba[PADIDX(t + (pp << 6))]; xb[pp] = Bb[PADIDX(t + (pp << 6))]; }
        dft8(xa, ya);
        dft8(xb, yb);
    }
    __syncthreads();
    #pragma unroll
    for (int q = 0; q < 8; ++q) {
        Ba[PADIDX(t + (q << 6))] = ya[q];
        Bb[PADIDX(t + (q << 6))] = yb[q];
    }
    __syncthreads();
    {
        int c = tid & 7, r0 = tid >> 3;
        int colg = COLG(c);
        int mc = 7 - c;
        if (g == 0) { if (c == 0) mc = 0; else if (c == 7) mc = 7; }
        #pragma unroll
        for (int k = 0; k < 16; ++k) {
            int rr = r0 + (k << 5);
            int mr = (512 - rr) & 511;
            float2 Z = B[c][PADIDX(rr)];
            float2 M = B[mc][PADIDX(mr)];
            float2 K0 = make_float2(0.5f * (Z.x + M.x), 0.5f * (Z.y - M.y));
            float2 K1 = make_float2(0.5f * (Z.y + M.y), 0.5f * (M.x - Z.x));
            size_t off = ((size_t)rr << 9) + colg;
            Kb0[off] = K0;
            Kb1[off] = K1;
        }
    }
    #undef COLG
}

// ---------------------------------------------------------------- pass 3
// Quad-cooperative KB gather, ISA-level pipeline (verified r3 version).
#define ISSUE(i, V0, V1, V2, V3, V4, V5) do {                               \
    float tm1 = r1v[i] * SCALE, tm2 = r2v[i] * SCALE;                       \
    float f1 = floorf(tm1), f2 = floorf(tm2);                               \
    int if1 = (int)f1, if2 = (int)f2;                                       \
    int e0 = (if2 - 2) & ~1;              /* even base col */               \
    int cpair = (e0 + j2) & 511;          /* even → pair never wraps mid */ \
    const float* pb = Kf + (cpair << 1);                                    \
    GLOAD4(V0, pb + (((if1 - 2) & 511) << 10));                             \
    GLOAD4(V1, pb + (((if1 - 1) & 511) << 10));                             \
    GLOAD4(V2, pb + (((if1    ) & 511) << 10));                             \
    GLOAD4(V3, pb + (((if1 + 1) & 511) << 10));                             \
    GLOAD4(V4, pb + (((if1 + 2) & 511) << 10));                             \
    GLOAD4(V5, pb + (((if1 + 3) & 511) << 10));                             \
    fr1v[i] = tm1 - f1;                                                     \
    u2v[i]  = tm2 - (float)(e0 + j2);                                       \
    SBAR();                                                                 \
} while (0)

#define WEIGHTS(i)                                                          \
    float u2_##i  = u2v[i];                                                 \
    float w2a_##i = kbw(u2_##i);                                            \
    float w2b_##i = kbw(u2_##i - 1.0f);                                     \
    float w1A_##i = kbw(fr1v[i] - fjm2);                                    \
    float w1B_##i = kbw(fr1v[i] - fjp2);                                    \
    float w0_##i = qdpp<0x00>(w1A_##i);                                     \
    float w1_##i = qdpp<0x55>(w1A_##i);                                     \
    float w2_##i = qdpp<0xAA>(w1A_##i);                                     \
    float w3_##i = qdpp<0xFF>(w1A_##i);                                     \
    float w4_##i = qdpp<0x00>(w1B_##i);                                     \
    float w5_##i = qdpp<0x55>(w1B_##i);

#define FMACONS(i, V0, V1, V2, V3, V4, V5) do {                             \
    float c0re = w0_##i * V0.x, c0im = w0_##i * V0.y;                       \
    float c1re = w0_##i * V0.z, c1im = w0_##i * V0.w;                       \
    c0re = fmaf(w1_##i, V1.x, c0re); c0im = fmaf(w1_##i, V1.y, c0im);       \
    c1re = fmaf(w1_##i, V1.z, c1re); c1im = fmaf(w1_##i, V1.w, c1im);       \
    c0re = fmaf(w2_##i, V2.x, c0re); c0im = fmaf(w2_##i, V2.y, c0im);       \
    c1re = fmaf(w2_##i, V2.z, c1re); c1im = fmaf(w2_##i, V2.w, c1im);       \
    c0re = fmaf(w3_##i, V3.x, c0re); c0im = fmaf(w3_##i, V3.y, c0im);       \
    c1re = fmaf(w3_##i, V3.z, c1re); c1im = fmaf(w3_##i, V3.w, c1im);       \
    c0re = fmaf(w4_##i, V4.x, c0re); c0im = fmaf(w4_##i, V4.y, c0im);       \
    c1re = fmaf(w4_##i, V4.z, c1re); c1im = fmaf(w4_##i, V4.w, c1im);       \
    c0re = fmaf(w5_##i, V5.x, c0re); c0im = fmaf(w5_##i, V5.y, c0im);       \
    c1re = fmaf(w5_##i, V5.z, c1re); c1im = fmaf(w5_##i, V5.w, c1im);       \
    float p_re = fmaf(w2a_##i, c0re, w2b_##i * c1re);                       \
    float p_im = fmaf(w2a_##i, c0im, w2b_##i * c1im);                       \
    p_re += qdpp<0xB1>(p_re); p_re += qdpp<0x4E>(p_re);                     \
    p_im += qdpp<0xB1>(p_im); p_im += qdpp<0x4E>(p_im);                     \
    int mmm = m0 + ((i) << 6);                                              \
    float sre = p_re * rdv[i], sim = p_im * rdv[i];                         \
    if (j == 0) GSTORE1(sre, out_re + mmm);                                 \
    if (j == 1) GSTORE1(sim, out_im + mmm);                                 \
} while (0)

__global__ __launch_bounds__(256) void interp_kb(const float* __restrict__ ktraj,
                                                 const float* __restrict__ dcf,
                                                 const float2* __restrict__ kgrid,
                                                 float* __restrict__ out) {
    int tid = threadIdx.x;
    int blk = blockIdx.x;
    int b = blk & 7;                          // XCD affinity
    int gb = blk >> 3;                        // 0..255
    int j = tid & 3;                          // lane within quad
    int q = tid >> 2;                         // quad in block 0..63
    int j2 = j << 1;
    float fjm2 = (float)(j - 2), fjp2 = (float)(j + 2);

    const float SCALE = (float)GSZ / (2.0f * PI_F);
    const float* Kf = (const float*)(kgrid + ((size_t)b << 18));
    const float* kt1 = ktraj + ((size_t)(b * 2)) * MPTS;
    const float* kt2 = kt1 + MPTS;
    const float* dcfb = dcf + ((size_t)b << 17);
    float* out_re = out + ((size_t)b << 17);
    float* out_im = out_re + (size_t)NBATCH * MPTS;

    int m0 = (gb << 9) + q;                   // block covers 512 points

    float r1v[8], r2v[8], rdv[8];
    #define LOADPT(i) do {                     \
        GLOAD1(r1v[i], kt1 + m0 + ((i) << 6)); \
        GLOAD1(r2v[i], kt2 + m0 + ((i) << 6)); \
        GLOAD1(rdv[i], dcfb + m0 + ((i) << 6)); } while (0)
    LOADPT(0); LOADPT(1); LOADPT(2); LOADPT(3);
    LOADPT(4); LOADPT(5); LOADPT(6); LOADPT(7);
    #undef LOADPT
    WAITVM(0);

    float fr1v[8], u2v[8];
    f32x4 A0, A1, A2, A3, A4, A5;
    f32x4 B0, B1, B2, B3, B4, B5;

    ISSUE(0, A0, A1, A2, A3, A4, A5);
    ISSUE(1, B0, B1, B2, B3, B4, B5);

    // stage 0
    WEIGHTS(0);
    WAITVM(6);
    FMACONS(0, A0, A1, A2, A3, A4, A5);
    // stage 1
    ISSUE(2, A0, A1, A2, A3, A4, A5);
    WEIGHTS(1);
    WAITVM(6);
    FMACONS(1, B0, B1, B2, B3, B4, B5);
    // stage 2
    ISSUE(3, B0, B1, B2, B3, B4, B5);
    WEIGHTS(2);
    WAITVM(6);
    FMACONS(2, A0, A1, A2, A3, A4, A5);
    // stage 3
    ISSUE(4, A0, A1, A2, A3, A4, A5);
    WEIGHTS(3);
    WAITVM(6);
    FMACONS(3, B0, B1, B2, B3, B4, B5);
    // stage 4
    ISSUE(5, B0, B1, B2, B3, B4, B5);
    WEIGHTS(4);
    WAITVM(6);
    FMACONS(4, A0, A1, A2, A3, A4, A5);
    // stage 5
    ISSUE(6, A0, A1, A2, A3, A4, A5);
    WEIGHTS(5);
    WAITVM(6);
    FMACONS(5, B0, B1, B2, B3, B4, B5);
    // stage 6
    ISSUE(7, B0, B1, B2, B3, B4, B5);
    WEIGHTS(6);
    WAITVM(6);
    FMACONS(6, A0, A1, A2, A3, A4, A5);
    // stage 7
    WEIGHTS(7);
    WAITVM(0);
    FMACONS(7, B0, B1, B2, B3, B4, B5);

    WAITVM(0);  // drain stores before exit (defensive)
}

// ---------------------------------------------------------------- launch

extern "C" void kernel_launch(void* const* d_in, const int* in_sizes, int n_in,
                              void* d_out, int out_size, void* d_ws, size_t ws_size,
                              hipStream_t stream) {
    const float* image = (const float*)d_in[0];   // (8,256,256) f32
    const float* ktraj = (const float*)d_in[1];   // (8,2,131072) f32
    const float* dcf   = (const float*)d_in[2];   // (8,131072) f32
    float* out = (float*)d_out;                   // (2,8,131072) f32

    float2* T     = (float2*)d_ws;                        // 4 pairs *256*512 c64 = 4.2 MB
    float2* kgrid = T + (size_t)4 * 256 * GSZ;            // 8*512*512 c64 = 16.8 MB

    pass1_rowfft<<<512, 256, 0, stream>>>(image, T);      // 2 rows/block, 128 thr/row
    pass2_colfft<<<256, 256, 0, stream>>>(T, kgrid);      // 4 pairs * 512 cols / 8 per block
    interp_kb<<<NBATCH * 256, 256, 0, stream>>>(ktraj, dcf, kgrid, out);
}